// Round 1
// 561.041 us; speedup vs baseline: 1.0182x; 1.0182x over previous
//
#include <hip/hip_runtime.h>
#include <stdint.h>

#define BATCH 512
#define FEAT 512
#define NCLS 100000
#define BM 128
#define BN 128
#define BK 64
#define NBLK_N 782            // ceil(100000/128)
#define NBLK (NBLK_N * 4)     // 3128 total blocks, divisible by 8 (XCD count)
#define NCHUNK (NBLK_N * 2)   // per-row softmax partial chunks (one per 64-col wave tile)
#define SCALE_S 32.0f
#define MARGIN 0.5f
#define MM_CONST 0.23971276930210156f  // 0.5*sin(pi-0.5)
#define PI_F 3.14159265358979f

typedef unsigned int u32;
typedef unsigned short u16;
typedef __bf16 bf16x8 __attribute__((ext_vector_type(8)));
typedef float f32x4 __attribute__((ext_vector_type(4)));

__device__ __forceinline__ u16 f2bf(float f) {
  u32 u = __float_as_uint(f);
  u += 0x7fffu + ((u >> 16) & 1u);
  return (u16)(u >> 16);
}

__device__ __forceinline__ void async_copy16(const void* g, void* l) {
  __builtin_amdgcn_global_load_lds((const __attribute__((address_space(1))) u32*)g,
                                   (__attribute__((address_space(3))) u32*)l,
                                   16, 0, 0);
}

__device__ __forceinline__ float block_reduce_sum(float v, float* sbuf) {
  for (int off = 1; off < 64; off <<= 1) v += __shfl_xor(v, off, 64);
  int wid = threadIdx.x >> 6, lane = threadIdx.x & 63;
  __syncthreads();
  if (lane == 0) sbuf[wid] = v;
  __syncthreads();
  return sbuf[0] + sbuf[1] + sbuf[2] + sbuf[3];
}

// Fused L2-normalize of inputs (BATCH rows) and weight (NCLS rows), f32 -> bf16.
// One wave per row, grid-stride; no LDS, no barriers; float4 loads, ushort4 stores.
__global__ __launch_bounds__(256) void norm_all_kernel(const float* __restrict__ inputs,
                                                       const float* __restrict__ weight,
                                                       u16* __restrict__ dstA,
                                                       u16* __restrict__ dstB) {
  const int lane = threadIdx.x & 63;
  const int gw = (blockIdx.x * 256 + threadIdx.x) >> 6;  // global wave id
  const int nw = gridDim.x * 4;                          // total waves
  for (int row = gw; row < BATCH + NCLS; row += nw) {
    const float* src;
    u16* dst;
    if (row < BATCH) {
      src = inputs + (size_t)row * FEAT;
      dst = dstA + (size_t)row * FEAT;
    } else {
      src = weight + (size_t)(row - BATCH) * FEAT;
      dst = dstB + (size_t)(row - BATCH) * FEAT;
    }
    const float4* p4 = (const float4*)src;
    float4 a = p4[lane];        // elements 4*lane .. 4*lane+3
    float4 b = p4[lane + 64];   // elements 256+4*lane ..
    float ss = a.x * a.x + a.y * a.y + a.z * a.z + a.w * a.w +
               b.x * b.x + b.y * b.y + b.z * b.z + b.w * b.w;
#pragma unroll
    for (int off = 1; off < 64; off <<= 1) ss += __shfl_xor(ss, off, 64);
    float inv = 1.0f / fmaxf(sqrtf(ss), 1e-12f);
    ushort4 oa, ob;
    oa.x = f2bf(a.x * inv); oa.y = f2bf(a.y * inv);
    oa.z = f2bf(a.z * inv); oa.w = f2bf(a.w * inv);
    ob.x = f2bf(b.x * inv); ob.y = f2bf(b.y * inv);
    ob.z = f2bf(b.z * inv); ob.w = f2bf(b.w * inv);
    ((ushort4*)dst)[lane] = oa;
    ((ushort4*)dst)[lane + 64] = ob;
  }
}

// C[512 x 100000] = Ahat @ Bhat^T (bf16 MFMA), fused clip/margin/scale epilogue,
// writes outs and per-(row, 64-col-chunk) online-softmax partials (max, sumexp).
// Double-buffered LDS, counted vmcnt prefetch (never drains to 0 in main loop),
// XCD-chunked block swizzle so the 4 M-blocks sharing a B-tile run adjacently
// on the same XCD's L2.
__global__ __launch_bounds__(256) void gemm_kernel(const u16* __restrict__ A,
                                                   const u16* __restrict__ B,
                                                   const int* __restrict__ labels,
                                                   float* __restrict__ outs,
                                                   float* __restrict__ partials) {
  __shared__ __align__(16) u16 sA[2][BM * BK];
  __shared__ __align__(16) u16 sB[2][BN * BK];
  __shared__ int sLab[BM];

  const int tid = threadIdx.x;
  const int lane = tid & 63;
  const int wid = tid >> 6;
  const int waveM = wid >> 1, waveN = wid & 1;
  // bijective XCD swizzle: NBLK % 8 == 0; XCD x processes logical ids
  // [x*NBLK/8, (x+1)*NBLK/8); logical order is m-fastest so the 4 B-tile
  // sharers are temporally adjacent on one XCD.
  const int orig = blockIdx.x;
  const int L = (orig & 7) * (NBLK / 8) + (orig >> 3);
  const int bm = L & 3, bn = L >> 2;
  const int quad = lane >> 4, l15 = lane & 15;

  if (tid < BM) sLab[tid] = labels[bm * BM + tid];

  // staging map: LDS 16B-block index idx16 holds global (row=idx16>>3, colblock=(idx16&7)^(row&7))
  const u16* gA[4];
  const u16* gB[4];
#pragma unroll
  for (int rd = 0; rd < 4; ++rd) {
    int idx = rd * 256 + tid;
    int r = idx >> 3;
    int cb = (idx & 7) ^ (r & 7);
    gA[rd] = A + (size_t)(bm * BM + r) * FEAT + cb * 8;
    int brow = bn * BN + r;
    if (brow >= NCLS) brow = NCLS - 1;  // clamp; masked in epilogue
    gB[rd] = B + (size_t)brow * FEAT + cb * 8;
  }

#define STAGE(buf, kt)                                      \
  do {                                                      \
    _Pragma("unroll") for (int rd = 0; rd < 4; ++rd) {      \
      int li = (rd * 256 + tid) * 8;                        \
      async_copy16(gA[rd] + (kt)*BK, &sA[buf][li]);         \
      async_copy16(gB[rd] + (kt)*BK, &sB[buf][li]);         \
    }                                                       \
  } while (0)

  f32x4 acc[4][4] = {};

  STAGE(0, 0);
  __syncthreads();  // drains vmcnt(0)+lgkmcnt(0): buf0 + sLab ready

  int cur = 0;
#pragma unroll
  for (int kt = 0; kt < FEAT / BK; ++kt) {
    if (kt < FEAT / BK - 1) {
      STAGE(cur ^ 1, kt + 1);  // 8 loads/wave stay in flight across the barrier
      asm volatile("s_waitcnt vmcnt(8)" ::: "memory");  // current buf's 8 done
    } else {
      asm volatile("s_waitcnt vmcnt(0)" ::: "memory");
    }
    asm volatile("s_barrier" ::: "memory");  // all waves' current-buf loads landed
#pragma unroll
    for (int ks = 0; ks < 2; ++ks) {
      int j0 = ks * 4 + quad;
      bf16x8 aF[4], bF[4];
#pragma unroll
      for (int mi = 0; mi < 4; ++mi) {
        int r = waveM * 64 + mi * 16 + l15;
        aF[mi] = *(const bf16x8*)&sA[cur][(r * 8 + (j0 ^ (r & 7))) * 8];
      }
#pragma unroll
      for (int ni = 0; ni < 4; ++ni) {
        int r = waveN * 64 + ni * 16 + l15;
        bF[ni] = *(const bf16x8*)&sB[cur][(r * 8 + (j0 ^ (r & 7))) * 8];
      }
#pragma unroll
      for (int mi = 0; mi < 4; ++mi)
#pragma unroll
        for (int ni = 0; ni < 4; ++ni)
          acc[mi][ni] = __builtin_amdgcn_mfma_f32_16x16x32_bf16(aF[mi], bF[ni],
                                                                acc[mi][ni], 0, 0, 0);
    }
    asm volatile("s_barrier" ::: "memory");  // all waves done reading cur before overwrite
    cur ^= 1;
  }
#undef STAGE

  // epilogue: clip, margin at label col, scale, store, softmax partials
#pragma unroll
  for (int mi = 0; mi < 4; ++mi) {
#pragma unroll
    for (int reg = 0; reg < 4; ++reg) {
      int rloc = waveM * 64 + mi * 16 + quad * 4 + reg;
      int rg = bm * BM + rloc;
      int lab = sLab[rloc];
      float vals[4];
      float rmax = -1e30f;
#pragma unroll
      for (int ni = 0; ni < 4; ++ni) {
        int cg = bn * BN + waveN * 64 + ni * 16 + l15;
        float v = acc[mi][ni][reg];
        v = fminf(fmaxf(v, -1.0f + 1e-6f), 1.0f - 1e-6f);
        if (cg == lab) {  // cos(arccos(x))==x elsewhere; only label col needs transcendentals
          float th = acosf(v) + MARGIN;
          v = (th < PI_F) ? cosf(th) : (v - MM_CONST);
        }
        v *= SCALE_S;
        if (cg < NCLS)
          outs[(size_t)rg * NCLS + cg] = v;
        else
          v = -1e30f;  // OOB logit: vanishes in online-softmax combine
        vals[ni] = v;
        rmax = fmaxf(rmax, v);
      }
#pragma unroll
      for (int off = 1; off < 16; off <<= 1) rmax = fmaxf(rmax, __shfl_xor(rmax, off, 64));
      float rsum = 0.f;
#pragma unroll
      for (int ni = 0; ni < 4; ++ni) rsum += __expf(vals[ni] - rmax);
#pragma unroll
      for (int off = 1; off < 16; off <<= 1) rsum += __shfl_xor(rsum, off, 64);
      if (l15 == 0) {
        float* p = partials + ((size_t)rg * NCHUNK + (bn * 2 + waveN)) * 2;
        p[0] = rmax;
        p[1] = rsum;
      }
    }
  }
}

// per-row: merge NCHUNK (max,sumexp) partials -> lse; loss_r = lse - outs[r, label[r]]
__global__ __launch_bounds__(256) void combine_kernel(const float* __restrict__ partials,
                                                      const float* __restrict__ outs,
                                                      const int* __restrict__ labels,
                                                      float* __restrict__ loss_r) {
  int r = blockIdx.x, tid = threadIdx.x;
  const float* p = partials + (size_t)r * NCHUNK * 2;
  float m = -1e30f, l = 0.f;
  for (int i = tid; i < NCHUNK; i += 256) {
    float mi = p[2 * i], li = p[2 * i + 1];
    if (mi > m) { l = l * __expf(m - mi) + li; m = mi; }
    else l += li * __expf(mi - m);
  }
  for (int off = 1; off < 64; off <<= 1) {
    float mo = __shfl_xor(m, off, 64);
    float lo = __shfl_xor(l, off, 64);
    if (mo > m) { l = l * __expf(m - mo) + lo; m = mo; }
    else l += lo * __expf(mo - m);
  }
  __shared__ float sm[4], sl[4];
  int wv = tid >> 6, lane = tid & 63;
  if (lane == 0) { sm[wv] = m; sl[wv] = l; }
  __syncthreads();
  if (tid == 0) {
    for (int w = 1; w < 4; ++w) {
      float mo = sm[w], lo = sl[w];
      if (mo > m) { l = l * __expf(m - mo) + lo; m = mo; }
      else l += lo * __expf(mo - m);
    }
    float lse = m + logf(l);
    loss_r[r] = lse - outs[(size_t)r * NCLS + labels[r]];
  }
}

__global__ __launch_bounds__(256) void loss_kernel(const float* __restrict__ loss_r,
                                                   float* __restrict__ out0) {
  __shared__ float sbuf[4];
  float v = loss_r[threadIdx.x] + loss_r[threadIdx.x + 256];
  float s = block_reduce_sum(v, sbuf);
  if (threadIdx.x == 0) out0[0] = s * (1.0f / BATCH);
}

// exact f32 recompute of target_cos_in / target_theta_in / target_cos_out
__global__ __launch_bounds__(256) void targets_kernel(const float* __restrict__ inputs,
                                                      const int* __restrict__ labels,
                                                      const float* __restrict__ weight,
                                                      float* __restrict__ tdst) {
  __shared__ float sbuf[4];
  int r = blockIdx.x, t = threadIdx.x;
  int lab = labels[r];
  const float2* px = (const float2*)(inputs + (size_t)r * FEAT);
  const float2* pw = (const float2*)(weight + (size_t)lab * FEAT);
  float2 x = px[t], w = pw[t];
  float dot = block_reduce_sum(x.x * w.x + x.y * w.y, sbuf);
  float sx = block_reduce_sum(x.x * x.x + x.y * x.y, sbuf);
  float sw = block_reduce_sum(w.x * w.x + w.y * w.y, sbuf);
  if (t == 0) {
    float inv = 1.0f / (fmaxf(sqrtf(sx), 1e-12f) * fmaxf(sqrtf(sw), 1e-12f));
    float ci = fminf(fmaxf(dot * inv, -1.0f + 1e-6f), 1.0f - 1e-6f);
    float th = acosf(ci);
    float t2 = th + MARGIN;
    float co = (t2 < PI_F) ? cosf(t2) : (ci - MM_CONST);
    tdst[r] = ci;
    tdst[BATCH + r] = th;
    tdst[2 * BATCH + r] = co;
  }
}

extern "C" void kernel_launch(void* const* d_in, const int* in_sizes, int n_in,
                              void* d_out, int out_size, void* d_ws, size_t ws_size,
                              hipStream_t stream) {
  const float* inputs = (const float*)d_in[0];
  const int* labels = (const int*)d_in[1];
  const float* weight = (const float*)d_in[2];
  float* out = (float*)d_out;
  float* outs = out + 1;                                // [512][100000]
  float* tdst = out + 1 + (size_t)BATCH * NCLS;         // 3 x [512]

  // workspace layout (~104.3 MiB total)
  char* ws = (char*)d_ws;
  u16* wsA = (u16*)ws;                                  // 512*512*2      = 524288 B
  u16* wsB = (u16*)(ws + 524288);                       // 100000*512*2   = 102400000 B
  float* partials = (float*)(ws + 524288 + 102400000);  // 512*1564*2*4   = 6406144 B
  float* loss_r = (float*)(ws + 524288 + 102400000 + (size_t)BATCH * NCHUNK * 2 * 4);

  norm_all_kernel<<<2048, 256, 0, stream>>>(inputs, weight, wsA, wsB);
  gemm_kernel<<<NBLK, 256, 0, stream>>>(wsA, wsB, labels, outs, partials);
  combine_kernel<<<BATCH, 256, 0, stream>>>(partials, outs, labels, loss_r);
  loss_kernel<<<1, 256, 0, stream>>>(loss_r, out);
  targets_kernel<<<BATCH, 256, 0, stream>>>(inputs, labels, weight, tdst);
}

// Round 2
// 507.339 us; speedup vs baseline: 1.1259x; 1.1059x over previous
//
#include <hip/hip_runtime.h>
#include <stdint.h>

#define BATCH 512
#define FEAT 512
#define NCLS 100000
#define BM 128
#define BN 128
#define BK 64
#define NBLK_N 782            // ceil(100000/128)
#define NBLK (NBLK_N * 4)     // 3128 total blocks, divisible by 8 (XCD count)
#define NCHUNK (NBLK_N * 2)   // per-row softmax partial chunks (one per 64-col wave tile)
#define SCALE_S 32.0f
#define MARGIN 0.5f
#define MM_CONST 0.23971276930210156f  // 0.5*sin(pi-0.5)
#define PI_F 3.14159265358979f

typedef unsigned int u32;
typedef unsigned short u16;
typedef __bf16 bf16x8 __attribute__((ext_vector_type(8)));
typedef float f32x4 __attribute__((ext_vector_type(4)));

__device__ __forceinline__ u16 f2bf(float f) {
  u32 u = __float_as_uint(f);
  u += 0x7fffu + ((u >> 16) & 1u);
  return (u16)(u >> 16);
}

__device__ __forceinline__ void async_copy16(const void* g, void* l) {
  __builtin_amdgcn_global_load_lds((const __attribute__((address_space(1))) u32*)g,
                                   (__attribute__((address_space(3))) u32*)l,
                                   16, 0, 0);
}

__device__ __forceinline__ float block_reduce_sum(float v, float* sbuf) {
  for (int off = 1; off < 64; off <<= 1) v += __shfl_xor(v, off, 64);
  int wid = threadIdx.x >> 6, lane = threadIdx.x & 63;
  __syncthreads();
  if (lane == 0) sbuf[wid] = v;
  __syncthreads();
  return sbuf[0] + sbuf[1] + sbuf[2] + sbuf[3];
}

// Fused L2-normalize of inputs (BATCH rows) and weight (NCLS rows), f32 -> bf16.
// One wave per row, grid-stride; no LDS, no barriers; float4 loads, ushort4 stores.
// Also zeroes out[0] (loss accumulator used by combine_kernel's atomicAdd).
__global__ __launch_bounds__(256) void norm_all_kernel(const float* __restrict__ inputs,
                                                       const float* __restrict__ weight,
                                                       u16* __restrict__ dstA,
                                                       u16* __restrict__ dstB,
                                                       float* __restrict__ out0) {
  if (blockIdx.x == 0 && threadIdx.x == 0) out0[0] = 0.0f;
  const int lane = threadIdx.x & 63;
  const int gw = (blockIdx.x * 256 + threadIdx.x) >> 6;  // global wave id
  const int nw = gridDim.x * 4;                          // total waves
  for (int row = gw; row < BATCH + NCLS; row += nw) {
    const float* src;
    u16* dst;
    if (row < BATCH) {
      src = inputs + (size_t)row * FEAT;
      dst = dstA + (size_t)row * FEAT;
    } else {
      src = weight + (size_t)(row - BATCH) * FEAT;
      dst = dstB + (size_t)(row - BATCH) * FEAT;
    }
    const float4* p4 = (const float4*)src;
    float4 a = p4[lane];        // elements 4*lane .. 4*lane+3
    float4 b = p4[lane + 64];   // elements 256+4*lane ..
    float ss = a.x * a.x + a.y * a.y + a.z * a.z + a.w * a.w +
               b.x * b.x + b.y * b.y + b.z * b.z + b.w * b.w;
#pragma unroll
    for (int off = 1; off < 64; off <<= 1) ss += __shfl_xor(ss, off, 64);
    float inv = 1.0f / fmaxf(sqrtf(ss), 1e-12f);
    ushort4 oa, ob;
    oa.x = f2bf(a.x * inv); oa.y = f2bf(a.y * inv);
    oa.z = f2bf(a.z * inv); oa.w = f2bf(a.w * inv);
    ob.x = f2bf(b.x * inv); ob.y = f2bf(b.y * inv);
    ob.z = f2bf(b.z * inv); ob.w = f2bf(b.w * inv);
    ((ushort4*)dst)[lane] = oa;
    ((ushort4*)dst)[lane + 64] = ob;
  }
}

// C[512 x 100000] = Ahat @ Bhat^T (bf16 MFMA), fused clip/margin/scale epilogue,
// writes outs and per-(row, 64-col-chunk) online-softmax partials (max, sumexp).
// v2 structure:
//  - A fragments loaded direct from global (A is 512 KB, L2-hot on every XCD);
//    only B is LDS-staged -> 33 KB LDS -> 4 blocks/CU by LDS, 3 by VGPR.
//  - B double-buffer as two DISTINCT __shared__ objects + manually unrolled
//    K-loop with compile-time buffer names, so alias analysis lets the
//    prefetch survive (no compiler vmcnt(0) drain per step).
//  - A-loads issued first, sched_barrier pins them before the staging ops so
//    the compiler's pre-MFMA wait is vmcnt(4) (leaves next tile in flight);
//    our vmcnt(12) retires exactly the current B tile (the oldest 4 loads).
__global__ __launch_bounds__(256, 3) void gemm_kernel(const u16* __restrict__ A,
                                                      const u16* __restrict__ B,
                                                      const int* __restrict__ labels,
                                                      float* __restrict__ outs,
                                                      float* __restrict__ partials) {
  __shared__ __align__(16) u16 sB0[BN * BK];
  __shared__ __align__(16) u16 sB1[BN * BK];
  __shared__ int sLab[BM];

  const int tid = threadIdx.x;
  const int lane = tid & 63;
  const int wid = tid >> 6;
  const int waveM = wid >> 1, waveN = wid & 1;
  // bijective XCD swizzle: NBLK % 8 == 0; XCD x processes logical ids
  // [x*NBLK/8, (x+1)*NBLK/8); logical order is m-fastest so the 4 B-tile
  // sharers are temporally adjacent on one XCD.
  const int orig = blockIdx.x;
  const int L = (orig & 7) * (NBLK / 8) + (orig >> 3);
  const int bm = L & 3, bn = L >> 2;
  const int quad = lane >> 4, l15 = lane & 15;

  if (tid < BM) sLab[tid] = labels[bm * BM + tid];

  // B staging map: LDS 16B-block index idx16 holds global
  // (row = idx16>>3, colblock = (idx16&7)^(row&7))
  const u16* gB[4];
#pragma unroll
  for (int rd = 0; rd < 4; ++rd) {
    int idx = rd * 256 + tid;
    int r = idx >> 3;
    int cb = (idx & 7) ^ (r & 7);
    int brow = bn * BN + r;
    if (brow >= NCLS) brow = NCLS - 1;  // clamp; masked in epilogue
    gB[rd] = B + (size_t)brow * FEAT + cb * 8;
  }
  // A fragment base: row (within tile) = waveM*64 + mi*16 + l15
  const u16* gA = A + (size_t)(bm * BM + waveM * 64 + l15) * FEAT;

  f32x4 acc[4][4] = {};

#define STAGE_B(SBUF, KT)                                         \
  do {                                                            \
    _Pragma("unroll") for (int rd = 0; rd < 4; ++rd)              \
        async_copy16(gB[rd] + (KT)*BK, &(SBUF)[(rd * 256 + tid) * 8]); \
  } while (0)

  // One K-step: compute tile KT from SBUF_CUR, prefetch tile KT+1 into SBUF_NXT.
#define K_STEP(SBUF_CUR, SBUF_NXT, KT, LAST)                                     \
  do {                                                                           \
    bf16x8 aF[4][2];                                                             \
    _Pragma("unroll") for (int mi = 0; mi < 4; ++mi)                             \
        _Pragma("unroll") for (int ks = 0; ks < 2; ++ks)                         \
            aF[mi][ks] = *(const bf16x8*)(gA + (size_t)mi * 16 * FEAT +          \
                                          (KT)*BK + (ks * 4 + quad) * 8);        \
    __builtin_amdgcn_sched_barrier(0); /* keep A-loads older than staging */     \
    if (!(LAST)) {                                                               \
      STAGE_B(SBUF_NXT, (KT) + 1);                                              \
      /* outstanding: curB(4,oldest) + A(8) + nxtB(4); retire curB+A only */     \
      asm volatile("s_waitcnt vmcnt(12)" ::: "memory");                          \
    } else {                                                                     \
      asm volatile("s_waitcnt vmcnt(8)" ::: "memory"); /* curB done */           \
    }                                                                            \
    asm volatile("s_barrier" ::: "memory"); /* all waves' curB DMA landed */     \
    _Pragma("unroll") for (int ks = 0; ks < 2; ++ks) {                           \
      int j0 = ks * 4 + quad;                                                    \
      bf16x8 bF[4];                                                              \
      _Pragma("unroll") for (int ni = 0; ni < 4; ++ni) {                         \
        int r = waveN * 64 + ni * 16 + l15;                                      \
        bF[ni] = *(const bf16x8*)&(SBUF_CUR)[(r * 8 + (j0 ^ (r & 7))) * 8];     \
      }                                                                          \
      _Pragma("unroll") for (int mi = 0; mi < 4; ++mi)                           \
          _Pragma("unroll") for (int ni = 0; ni < 4; ++ni)                       \
              acc[mi][ni] = __builtin_amdgcn_mfma_f32_16x16x32_bf16(             \
                  aF[mi][ks], bF[ni], acc[mi][ni], 0, 0, 0);                     \
    }                                                                            \
    asm volatile("s_barrier" ::: "memory"); /* done reading before overwrite */  \
  } while (0)

  STAGE_B(sB0, 0);
  __syncthreads();  // drains prologue DMA + sLab

  K_STEP(sB0, sB1, 0, false);
  K_STEP(sB1, sB0, 1, false);
  K_STEP(sB0, sB1, 2, false);
  K_STEP(sB1, sB0, 3, false);
  K_STEP(sB0, sB1, 4, false);
  K_STEP(sB1, sB0, 5, false);
  K_STEP(sB0, sB1, 6, false);
  K_STEP(sB1, sB0, 7, true);

#undef K_STEP
#undef STAGE_B

  // epilogue: clip, margin at label col, scale, store, softmax partials
#pragma unroll
  for (int mi = 0; mi < 4; ++mi) {
#pragma unroll
    for (int reg = 0; reg < 4; ++reg) {
      int rloc = waveM * 64 + mi * 16 + quad * 4 + reg;
      int rg = bm * BM + rloc;
      int lab = sLab[rloc];
      float vals[4];
      float rmax = -1e30f;
#pragma unroll
      for (int ni = 0; ni < 4; ++ni) {
        int cg = bn * BN + waveN * 64 + ni * 16 + l15;
        float v = acc[mi][ni][reg];
        v = fminf(fmaxf(v, -1.0f + 1e-6f), 1.0f - 1e-6f);
        if (cg == lab) {  // cos(arccos(x))==x elsewhere; only label col needs transcendentals
          float th = acosf(v) + MARGIN;
          v = (th < PI_F) ? cosf(th) : (v - MM_CONST);
        }
        v *= SCALE_S;
        if (cg < NCLS)
          outs[(size_t)rg * NCLS + cg] = v;
        else
          v = -1e30f;  // OOB logit: vanishes in online-softmax combine
        vals[ni] = v;
        rmax = fmaxf(rmax, v);
      }
#pragma unroll
      for (int off = 1; off < 16; off <<= 1) rmax = fmaxf(rmax, __shfl_xor(rmax, off, 64));
      float rsum = 0.f;
#pragma unroll
      for (int ni = 0; ni < 4; ++ni) rsum += __expf(vals[ni] - rmax);
#pragma unroll
      for (int off = 1; off < 16; off <<= 1) rsum += __shfl_xor(rsum, off, 64);
      if (l15 == 0) {
        float* p = partials + ((size_t)rg * NCHUNK + (bn * 2 + waveN)) * 2;
        p[0] = rmax;
        p[1] = rsum;
      }
    }
  }
}

// per-row r: (a) merge NCHUNK (max,sumexp) partials -> lse, accumulate mean loss
// into out[0] via atomicAdd; (b) exact f32 recompute of target_cos_in /
// target_theta_in / target_cos_out (fused former targets_kernel + loss_kernel).
__global__ __launch_bounds__(256) void combine_kernel(const float* __restrict__ partials,
                                                      const float* __restrict__ outs,
                                                      const int* __restrict__ labels,
                                                      const float* __restrict__ inputs,
                                                      const float* __restrict__ weight,
                                                      float* __restrict__ out0,
                                                      float* __restrict__ tdst) {
  __shared__ float sbuf[4];
  __shared__ float smx[4], slx[4];
  int r = blockIdx.x, tid = threadIdx.x;
  int lab = labels[r];

  // targets: three dot/norm reductions over the full 512-dim row (f32 exact)
  const float2* px = (const float2*)(inputs + (size_t)r * FEAT);
  const float2* pw = (const float2*)(weight + (size_t)lab * FEAT);
  float2 x = px[tid], w = pw[tid];
  float dot = block_reduce_sum(x.x * w.x + x.y * w.y, sbuf);
  float sx = block_reduce_sum(x.x * x.x + x.y * x.y, sbuf);
  float sw = block_reduce_sum(w.x * w.x + w.y * w.y, sbuf);

  // lse: merge the per-chunk online-softmax partials
  const float* p = partials + (size_t)r * NCHUNK * 2;
  float m = -1e30f, l = 0.f;
  for (int i = tid; i < NCHUNK; i += 256) {
    float mi = p[2 * i], li = p[2 * i + 1];
    if (mi > m) { l = l * __expf(m - mi) + li; m = mi; }
    else l += li * __expf(mi - m);
  }
  for (int off = 1; off < 64; off <<= 1) {
    float mo = __shfl_xor(m, off, 64);
    float lo = __shfl_xor(l, off, 64);
    if (mo > m) { l = l * __expf(m - mo) + lo; m = mo; }
    else l += lo * __expf(mo - m);
  }
  int wv = tid >> 6, lane = tid & 63;
  if (lane == 0) { smx[wv] = m; slx[wv] = l; }
  __syncthreads();
  if (tid == 0) {
    for (int wq = 1; wq < 4; ++wq) {
      float mo = smx[wq], lo = slx[wq];
      if (mo > m) { l = l * __expf(m - mo) + lo; m = mo; }
      else l += lo * __expf(mo - m);
    }
    float lse = m + logf(l);
    float tgt = outs[(size_t)r * NCLS + lab];
    atomicAdd(out0, (lse - tgt) * (1.0f / BATCH));

    float inv = 1.0f / (fmaxf(sqrtf(sx), 1e-12f) * fmaxf(sqrtf(sw), 1e-12f));
    float ci = fminf(fmaxf(dot * inv, -1.0f + 1e-6f), 1.0f - 1e-6f);
    float th = acosf(ci);
    float t2 = th + MARGIN;
    float co = (t2 < PI_F) ? cosf(t2) : (ci - MM_CONST);
    tdst[r] = ci;
    tdst[BATCH + r] = th;
    tdst[2 * BATCH + r] = co;
  }
}

extern "C" void kernel_launch(void* const* d_in, const int* in_sizes, int n_in,
                              void* d_out, int out_size, void* d_ws, size_t ws_size,
                              hipStream_t stream) {
  const float* inputs = (const float*)d_in[0];
  const int* labels = (const int*)d_in[1];
  const float* weight = (const float*)d_in[2];
  float* out = (float*)d_out;
  float* outs = out + 1;                                // [512][100000]
  float* tdst = out + 1 + (size_t)BATCH * NCLS;         // 3 x [512]

  // workspace layout (~104.3 MiB total)
  char* ws = (char*)d_ws;
  u16* wsA = (u16*)ws;                                  // 512*512*2      = 524288 B
  u16* wsB = (u16*)(ws + 524288);                       // 100000*512*2   = 102400000 B
  float* partials = (float*)(ws + 524288 + 102400000);  // 512*1564*2*4   = 6406144 B

  norm_all_kernel<<<2048, 256, 0, stream>>>(inputs, weight, wsA, wsB, out);
  gemm_kernel<<<NBLK, 256, 0, stream>>>(wsA, wsB, labels, outs, partials);
  combine_kernel<<<BATCH, 256, 0, stream>>>(partials, outs, labels, inputs, weight, out, tdst);
}